// Round 1
// baseline (2222.237 us; speedup 1.0000x reference)
//
#include <hip/hip_runtime.h>

#define EDGES 160000
#define NNODES 10000

__device__ __forceinline__ float fsigmoid(float x) {
    return 1.0f / (1.0f + __expf(-x));
}

// ---------------------------------------------------------------------------
// Stage A: per-edge MLP (32 -> 64 -> 64 -> 64, silu) + mix + atomic scatter
// into node accumulators (all segmented by idx_i, per the reference).
// One thread per edge. Weights accessed with wave-uniform addresses -> s_load.
// ---------------------------------------------------------------------------
extern "C" __global__ void __launch_bounds__(256)
k_mlp_scatter(const float* __restrict__ edge_sh,
              const float* __restrict__ edge_fea,
              const int* __restrict__ idx_i,
              const float* __restrict__ w1, const float* __restrict__ b1,
              const float* __restrict__ w2, const float* __restrict__ b2,
              const float* __restrict__ w3, const float* __restrict__ b3,
              float* __restrict__ nsI, float* __restrict__ nsJ,
              float* __restrict__ nvI, float* __restrict__ nvJ)
{
    const int e = blockIdx.x * 256 + threadIdx.x;

    float s[32];
    const float4* f4 = reinterpret_cast<const float4*>(edge_fea + (size_t)e * 80);
    #pragma unroll
    for (int q = 0; q < 8; ++q) {
        float4 v = f4[q];
        s[4*q+0] = v.x; s[4*q+1] = v.y; s[4*q+2] = v.z; s[4*q+3] = v.w;
    }

    float h[64];
    #pragma unroll
    for (int k = 0; k < 64; ++k) h[k] = b1[k];
    #pragma unroll
    for (int i = 0; i < 32; ++i) {
        const float si = s[i];
        #pragma unroll
        for (int k = 0; k < 64; ++k) h[k] = fmaf(si, w1[i*64+k], h[k]);
    }
    #pragma unroll
    for (int k = 0; k < 64; ++k) h[k] = h[k] * fsigmoid(h[k]);

    float h2[64];
    #pragma unroll
    for (int k = 0; k < 64; ++k) h2[k] = b2[k];
    #pragma unroll
    for (int i = 0; i < 64; ++i) {
        const float si = h[i];
        #pragma unroll
        for (int k = 0; k < 64; ++k) h2[k] = fmaf(si, w2[i*64+k], h2[k]);
    }
    #pragma unroll
    for (int k = 0; k < 64; ++k) h2[k] = h2[k] * fsigmoid(h2[k]);

    float wgt[64];
    #pragma unroll
    for (int k = 0; k < 64; ++k) wgt[k] = b3[k];
    #pragma unroll
    for (int i = 0; i < 64; ++i) {
        const float si = h2[i];
        #pragma unroll
        for (int k = 0; k < 64; ++k) wgt[k] = fmaf(si, w3[i*64+k], wgt[k]);
    }

    // mix: si = wgt[0:16]*sh0, vi = wgt[16:32]*sh[1:4], sj = wgt[32:48]*sh0,
    //      vj = wgt[48:64]*sh[1:4]; all scattered by idx_i (seg uses idx_i).
    const float4 sh = *reinterpret_cast<const float4*>(edge_sh + (size_t)e * 4);
    const int ni = idx_i[e];
    float* pSI = nsI + ni * 16;
    float* pSJ = nsJ + ni * 16;
    float* pVI = nvI + ni * 48;
    float* pVJ = nvJ + ni * 48;

    #pragma unroll
    for (int m = 0; m < 16; ++m) atomicAdd(pSI + m, wgt[m] * sh.x);
    #pragma unroll
    for (int m = 0; m < 16; ++m) {
        const float wv = wgt[16+m];
        atomicAdd(pVI + m*3 + 0, wv * sh.y);
        atomicAdd(pVI + m*3 + 1, wv * sh.z);
        atomicAdd(pVI + m*3 + 2, wv * sh.w);
    }
    #pragma unroll
    for (int m = 0; m < 16; ++m) atomicAdd(pSJ + m, wgt[32+m] * sh.x);
    #pragma unroll
    for (int m = 0; m < 16; ++m) {
        const float wv = wgt[48+m];
        atomicAdd(pVJ + m*3 + 0, wv * sh.y);
        atomicAdd(pVJ + m*3 + 1, wv * sh.z);
        atomicAdd(pVJ + m*3 + 2, wv * sh.w);
    }
}

// ---------------------------------------------------------------------------
// Stage B: gather S1/V1 (node sums) + S2/V2 (edge features) into LDS
// (transposed [feat][edge]), then the 4 einsum contractions as per-edge GEMV
// with wave-uniform scalar weight loads. 64 edges/block, 4 waves:
//   wave 0: o_s[ 0..23], wave 1: o_s[24..47]
//   wave 2: o_v[0..7][c], wave 3: o_v[8..15][c]
// Epilogue: silu / sigmoid-gate fusion + output write.
// ---------------------------------------------------------------------------
extern "C" __global__ void __launch_bounds__(256)
k_contract(const float* __restrict__ edge_fea,
           const int* __restrict__ idx_i,
           const int* __restrict__ idx_j,
           const float* __restrict__ nsI, const float* __restrict__ nsJ,
           const float* __restrict__ nvI, const float* __restrict__ nvJ,
           const float* __restrict__ w_ss, const float* __restrict__ w_vv,
           const float* __restrict__ w_sv, const float* __restrict__ w_vs,
           float* __restrict__ out)
{
    __shared__ float lds[13312];            // 53.25 KB -> 3 blocks/CU
    float* sS1 = lds;                       // [32][64]  i-major
    float* sS2 = lds + 2048;                // [32][64]  j-major
    float* sV1 = lds + 4096;                // [96][64]  (c*32+i)
    float* sV2 = lds + 10240;               // [48][64]  (c*16+j)
    float* sOs = lds + 4096;                // alias over sV1 rows 0..47
    float* sOv = lds + 7168;                // alias over sV1 rows 48..95

    const int tid = threadIdx.x;
    const int e0 = blockIdx.x * 64;
    const int lane = tid & 63;

    // ---- gather S2 / V2 from edge_fea ----
    for (int t = tid; t < 64*20; t += 256) {
        const int e = t & 63, q = t >> 6;
        const float4 v = *reinterpret_cast<const float4*>(
            edge_fea + (size_t)(e0 + e) * 80 + q * 4);
        const float vv[4] = {v.x, v.y, v.z, v.w};
        #pragma unroll
        for (int u = 0; u < 4; ++u) {
            const int f = q*4 + u;
            if (f < 32) {
                sS2[f*64 + e] = vv[u];
            } else {
                const int r = f - 32;           // r = j*3 + c
                sV2[((r % 3)*16 + (r / 3))*64 + e] = vv[u];
            }
        }
    }
    // ---- gather S1 ----
    for (int t = tid; t < 64*32; t += 256) {
        const int e = t & 63, i = t >> 6;
        float v;
        if (i < 16) v = nsI[idx_i[e0+e]*16 + i];
        else        v = nsJ[idx_j[e0+e]*16 + (i - 16)];
        sS1[i*64 + e] = v;
    }
    // ---- gather V1 ----
    for (int t = tid; t < 64*96; t += 256) {
        const int e = t & 63, r = t >> 6;   // r in [0,96): r = i*3+c
        const int i = r / 3, c = r % 3;
        float v;
        if (i < 16) v = nvI[(idx_i[e0+e]*16 + i)*3 + c];
        else        v = nvJ[(idx_j[e0+e]*16 + (i - 16))*3 + c];
        sV1[(c*32 + i)*64 + e] = v;
    }
    __syncthreads();

    const int w = __builtin_amdgcn_readfirstlane(tid >> 6);
    const float INV2 = 0.70710678118654752f;
    const float RS512 = 22.627416997969522f;     // sqrt(512)

    float acc[24];
    #pragma unroll
    for (int m = 0; m < 24; ++m) acc[m] = 0.0f;

    if (w < 2) {
        // ---------------- o_s: ss (K=1024) + vv (K=512) ----------------
        const int o0 = w * 24;
        const float aSS = INV2 / 32.0f;
        const float aVV = INV2 * 0.57735026918962576f / RS512;
        const float* wssb = w_ss + o0 * 1024;
        for (int i = 0; i < 32; ++i) {
            const float s1 = aSS * sS1[i*64 + lane];
            #pragma unroll 1
            for (int j = 0; j < 32; j += 4) {
                const float x0 = s1 * sS2[(j+0)*64 + lane];
                const float x1 = s1 * sS2[(j+1)*64 + lane];
                const float x2 = s1 * sS2[(j+2)*64 + lane];
                const float x3 = s1 * sS2[(j+3)*64 + lane];
                #pragma unroll
                for (int m = 0; m < 24; ++m) {
                    const float* wp = wssb + m*1024 + i*32 + j;
                    acc[m] = fmaf(x0, wp[0], acc[m]);
                    acc[m] = fmaf(x1, wp[1], acc[m]);
                    acc[m] = fmaf(x2, wp[2], acc[m]);
                    acc[m] = fmaf(x3, wp[3], acc[m]);
                }
            }
        }
        const float* wvvb = w_vv + o0 * 512;
        for (int i = 0; i < 32; ++i) {
            const float v1c0 = aVV * sV1[(0*32 + i)*64 + lane];
            const float v1c1 = aVV * sV1[(1*32 + i)*64 + lane];
            const float v1c2 = aVV * sV1[(2*32 + i)*64 + lane];
            #pragma unroll 1
            for (int j = 0; j < 16; j += 4) {
                float x[4];
                #pragma unroll
                for (int u = 0; u < 4; ++u) {
                    x[u] = v1c0 * sV2[(0*16 + j + u)*64 + lane]
                         + v1c1 * sV2[(1*16 + j + u)*64 + lane]
                         + v1c2 * sV2[(2*16 + j + u)*64 + lane];
                }
                #pragma unroll
                for (int m = 0; m < 24; ++m) {
                    const float* wp = wvvb + m*512 + i*16 + j;
                    acc[m] = fmaf(x[0], wp[0], acc[m]);
                    acc[m] = fmaf(x[1], wp[1], acc[m]);
                    acc[m] = fmaf(x[2], wp[2], acc[m]);
                    acc[m] = fmaf(x[3], wp[3], acc[m]);
                }
            }
        }
    } else {
        // ---------------- o_v: sv (K=512/c) + vs (K=1024/c) ----------------
        const int o0 = (w - 2) * 8;
        const float aSV = INV2 / RS512;
        const float aVS = INV2 / 32.0f;
        const float* wsvb = w_sv + o0 * 512;
        for (int i = 0; i < 32; ++i) {
            const float s1 = aSV * sS1[i*64 + lane];
            #pragma unroll 1
            for (int j = 0; j < 16; j += 4) {
                float x[4][3];
                #pragma unroll
                for (int u = 0; u < 4; ++u) {
                    x[u][0] = s1 * sV2[(0*16 + j + u)*64 + lane];
                    x[u][1] = s1 * sV2[(1*16 + j + u)*64 + lane];
                    x[u][2] = s1 * sV2[(2*16 + j + u)*64 + lane];
                }
                #pragma unroll
                for (int m = 0; m < 8; ++m) {
                    const float* wp = wsvb + m*512 + i*16 + j;
                    #pragma unroll
                    for (int u = 0; u < 4; ++u) {
                        const float wq = wp[u];
                        acc[m*3+0] = fmaf(x[u][0], wq, acc[m*3+0]);
                        acc[m*3+1] = fmaf(x[u][1], wq, acc[m*3+1]);
                        acc[m*3+2] = fmaf(x[u][2], wq, acc[m*3+2]);
                    }
                }
            }
        }
        const float* wvsb = w_vs + o0 * 1024;
        for (int i = 0; i < 32; ++i) {
            const float v1c0 = sV1[(0*32 + i)*64 + lane];
            const float v1c1 = sV1[(1*32 + i)*64 + lane];
            const float v1c2 = sV1[(2*32 + i)*64 + lane];
            #pragma unroll 1
            for (int j = 0; j < 32; j += 4) {
                float x[4][3];
                #pragma unroll
                for (int u = 0; u < 4; ++u) {
                    const float s2 = aVS * sS2[(j + u)*64 + lane];
                    x[u][0] = v1c0 * s2;
                    x[u][1] = v1c1 * s2;
                    x[u][2] = v1c2 * s2;
                }
                #pragma unroll
                for (int m = 0; m < 8; ++m) {
                    const float* wp = wvsb + m*1024 + i*32 + j;
                    #pragma unroll
                    for (int u = 0; u < 4; ++u) {
                        const float wq = wp[u];
                        acc[m*3+0] = fmaf(x[u][0], wq, acc[m*3+0]);
                        acc[m*3+1] = fmaf(x[u][1], wq, acc[m*3+1]);
                        acc[m*3+2] = fmaf(x[u][2], wq, acc[m*3+2]);
                    }
                }
            }
        }
    }

    __syncthreads();   // everyone done reading sV1/sV2 before we alias-write

    if (w < 2) {
        const int o0 = w * 24;
        #pragma unroll
        for (int m = 0; m < 24; ++m) sOs[(o0 + m)*64 + lane] = acc[m];
    } else {
        const int o0 = (w - 2) * 8;
        #pragma unroll
        for (int m = 0; m < 8; ++m) {
            #pragma unroll
            for (int c = 0; c < 3; ++c)
                sOv[((o0 + m)*3 + c)*64 + lane] = acc[m*3 + c];
        }
    }
    __syncthreads();

    // ---- epilogue: silu(o_s[:32]), o_v * sigmoid(o_s[32:48]) ----
    for (int t = tid; t < 64*80; t += 256) {
        const int e = t & 63, f = t >> 6;
        float r;
        if (f < 32) {
            const float x = sOs[f*64 + e];
            r = x * fsigmoid(x);
        } else {
            const int rr = f - 32;              // rr = o*3 + c
            const int o = rr / 3;
            r = sOv[rr*64 + e] * fsigmoid(sOs[(32 + o)*64 + e]);
        }
        out[(size_t)(e0 + e)*80 + f] = r;
    }
}

extern "C" void kernel_launch(void* const* d_in, const int* in_sizes, int n_in,
                              void* d_out, int out_size, void* d_ws, size_t ws_size,
                              hipStream_t stream)
{
    const float* edge_sh  = (const float*)d_in[0];
    const float* edge_fea = (const float*)d_in[1];
    const int*   eidx     = (const int*)d_in[2];
    // d_in[3] = batch_edge (unused)
    const float* w1 = (const float*)d_in[4];
    const float* b1 = (const float*)d_in[5];
    const float* w2 = (const float*)d_in[6];
    const float* b2 = (const float*)d_in[7];
    const float* w3 = (const float*)d_in[8];
    const float* b3 = (const float*)d_in[9];
    const float* w_ss = (const float*)d_in[10];
    const float* w_vv = (const float*)d_in[11];
    const float* w_sv = (const float*)d_in[12];
    const float* w_vs = (const float*)d_in[13];
    float* out = (float*)d_out;

    // workspace: node accumulators, 1,280,000 floats = 5.12 MB
    float* ws  = (float*)d_ws;
    float* nsI = ws;                 // [10000][16]
    float* nsJ = ws + 160000;        // [10000][16]
    float* nvI = ws + 320000;        // [10000][16][3]
    float* nvJ = ws + 800000;        // [10000][16][3]

    hipMemsetAsync(d_ws, 0, 1280000 * sizeof(float), stream);

    k_mlp_scatter<<<625, 256, 0, stream>>>(edge_sh, edge_fea, eidx,
                                           w1, b1, w2, b2, w3, b3,
                                           nsI, nsJ, nvI, nvJ);

    k_contract<<<2500, 256, 0, stream>>>(edge_fea, eidx, eidx + EDGES,
                                         nsI, nsJ, nvI, nvJ,
                                         w_ss, w_vv, w_sv, w_vs, out);
}

// Round 2
// 1269.095 us; speedup vs baseline: 1.7510x; 1.7510x over previous
//
#include <hip/hip_runtime.h>

#define EDGES 160000
#define NNODES 10000

__device__ __forceinline__ float fsigmoid(float x) {
    return 1.0f / (1.0f + __expf(-x));
}

// ---------------------------------------------------------------------------
// Shared MLP evaluation: edge e -> wgt[64]
// ---------------------------------------------------------------------------
__device__ __forceinline__ void mlp_eval(int e,
              const float* __restrict__ edge_fea,
              const float* __restrict__ w1, const float* __restrict__ b1,
              const float* __restrict__ w2, const float* __restrict__ b2,
              const float* __restrict__ w3, const float* __restrict__ b3,
              float* wgt)
{
    float s[32];
    const float4* f4 = reinterpret_cast<const float4*>(edge_fea + (size_t)e * 80);
    #pragma unroll
    for (int q = 0; q < 8; ++q) {
        float4 v = f4[q];
        s[4*q+0] = v.x; s[4*q+1] = v.y; s[4*q+2] = v.z; s[4*q+3] = v.w;
    }

    float h[64];
    #pragma unroll
    for (int k = 0; k < 64; ++k) h[k] = b1[k];
    #pragma unroll
    for (int i = 0; i < 32; ++i) {
        const float si = s[i];
        #pragma unroll
        for (int k = 0; k < 64; ++k) h[k] = fmaf(si, w1[i*64+k], h[k]);
    }
    #pragma unroll
    for (int k = 0; k < 64; ++k) h[k] = h[k] * fsigmoid(h[k]);

    float h2[64];
    #pragma unroll
    for (int k = 0; k < 64; ++k) h2[k] = b2[k];
    #pragma unroll
    for (int i = 0; i < 64; ++i) {
        const float si = h[i];
        #pragma unroll
        for (int k = 0; k < 64; ++k) h2[k] = fmaf(si, w2[i*64+k], h2[k]);
    }
    #pragma unroll
    for (int k = 0; k < 64; ++k) h2[k] = h2[k] * fsigmoid(h2[k]);

    #pragma unroll
    for (int k = 0; k < 64; ++k) wgt[k] = b3[k];
    #pragma unroll
    for (int i = 0; i < 64; ++i) {
        const float si = h2[i];
        #pragma unroll
        for (int k = 0; k < 64; ++k) wgt[k] = fmaf(si, w3[i*64+k], wgt[k]);
    }
}

// ---------------------------------------------------------------------------
// Fast path stage A: CSR build (hist/scan) + MLP->slot store + gather reduce
// ---------------------------------------------------------------------------
extern "C" __global__ void __launch_bounds__(256)
k_hist(const int* __restrict__ idx_i, int* __restrict__ counts)
{
    const int e = blockIdx.x * 256 + threadIdx.x;
    if (e < EDGES) atomicAdd(&counts[idx_i[e]], 1);
}

extern "C" __global__ void __launch_bounds__(256)
k_scan(const int* __restrict__ counts, int* __restrict__ offsets,
       int* __restrict__ cursor)
{
    __shared__ int sc[2][256];
    const int t = threadIdx.x;
    const int base = t * 40;
    int loc[40];
    int s = 0;
    #pragma unroll
    for (int k = 0; k < 40; ++k) {
        const int idx = base + k;
        const int c = (idx < NNODES) ? counts[idx] : 0;
        loc[k] = c; s += c;
    }
    sc[0][t] = s;
    __syncthreads();
    int src = 0;
    for (int off = 1; off < 256; off <<= 1) {
        int v = sc[src][t];
        if (t >= off) v += sc[src][t - off];
        sc[src ^ 1][t] = v;
        __syncthreads();
        src ^= 1;
    }
    int run = sc[src][t] - s;          // exclusive prefix
    #pragma unroll
    for (int k = 0; k < 40; ++k) {
        const int idx = base + k;
        if (idx < NNODES) {
            offsets[idx] = run;
            cursor[idx]  = run;
            run += loc[k];
        }
    }
    if (t == 255) offsets[NNODES] = EDGES;
}

extern "C" __global__ void __launch_bounds__(256)
k_mlp_store(const float* __restrict__ edge_sh,
            const float* __restrict__ edge_fea,
            const int* __restrict__ idx_i,
            const float* __restrict__ w1, const float* __restrict__ b1,
            const float* __restrict__ w2, const float* __restrict__ b2,
            const float* __restrict__ w3, const float* __restrict__ b3,
            int* __restrict__ cursor,
            float* __restrict__ wgtbuf, float* __restrict__ shbuf)
{
    const int e = blockIdx.x * 256 + threadIdx.x;
    float wgt[64];
    mlp_eval(e, edge_fea, w1, b1, w2, b2, w3, b3, wgt);

    const int ni = idx_i[e];
    const int slot = atomicAdd(&cursor[ni], 1);
    float4* wp = reinterpret_cast<float4*>(wgtbuf + (size_t)slot * 64);
    #pragma unroll
    for (int q = 0; q < 16; ++q)
        wp[q] = make_float4(wgt[4*q], wgt[4*q+1], wgt[4*q+2], wgt[4*q+3]);
    *reinterpret_cast<float4*>(shbuf + (size_t)slot * 4) =
        *reinterpret_cast<const float4*>(edge_sh + (size_t)e * 4);
}

// 2 nodes per 256-thread block; 128 threads per node = its 128 accum features.
extern "C" __global__ void __launch_bounds__(256)
k_reduce(const int* __restrict__ offsets,
         const float* __restrict__ wgtbuf, const float* __restrict__ shbuf,
         float* __restrict__ nsI, float* __restrict__ nsJ,
         float* __restrict__ nvI, float* __restrict__ nvJ)
{
    const int tid = threadIdx.x;
    const int n = blockIdx.x * 2 + (tid >> 7);
    const int o = tid & 127;

    int widx, shc;
    float* dst;
    if (o < 16)      { widx = o;            shc = 0;     dst = &nsI[n*16 + o]; }
    else if (o < 64) { const int r = o - 16; const int m = r / 3, c = r - 3*m;
                       widx = 16 + m;       shc = 1 + c; dst = &nvI[(n*16 + m)*3 + c]; }
    else if (o < 80) { const int r = o - 64;
                       widx = 32 + r;       shc = 0;     dst = &nsJ[n*16 + r]; }
    else             { const int r = o - 80; const int m = r / 3, c = r - 3*m;
                       widx = 48 + m;       shc = 1 + c; dst = &nvJ[(n*16 + m)*3 + c]; }

    const int s0 = offsets[n], s1 = offsets[n + 1];
    float acc = 0.0f;
    for (int s = s0; s < s1; ++s)
        acc = fmaf(wgtbuf[(size_t)s*64 + widx], shbuf[(size_t)s*4 + shc], acc);
    *dst = acc;
}

// ---------------------------------------------------------------------------
// Fallback stage A (atomic scatter) — used only if ws_size is too small.
// ---------------------------------------------------------------------------
extern "C" __global__ void __launch_bounds__(256)
k_mlp_scatter(const float* __restrict__ edge_sh,
              const float* __restrict__ edge_fea,
              const int* __restrict__ idx_i,
              const float* __restrict__ w1, const float* __restrict__ b1,
              const float* __restrict__ w2, const float* __restrict__ b2,
              const float* __restrict__ w3, const float* __restrict__ b3,
              float* __restrict__ nsI, float* __restrict__ nsJ,
              float* __restrict__ nvI, float* __restrict__ nvJ)
{
    const int e = blockIdx.x * 256 + threadIdx.x;
    float wgt[64];
    mlp_eval(e, edge_fea, w1, b1, w2, b2, w3, b3, wgt);

    const float4 sh = *reinterpret_cast<const float4*>(edge_sh + (size_t)e * 4);
    const int ni = idx_i[e];
    float* pSI = nsI + ni * 16;
    float* pSJ = nsJ + ni * 16;
    float* pVI = nvI + ni * 48;
    float* pVJ = nvJ + ni * 48;

    #pragma unroll
    for (int m = 0; m < 16; ++m) atomicAdd(pSI + m, wgt[m] * sh.x);
    #pragma unroll
    for (int m = 0; m < 16; ++m) {
        const float wv = wgt[16+m];
        atomicAdd(pVI + m*3 + 0, wv * sh.y);
        atomicAdd(pVI + m*3 + 1, wv * sh.z);
        atomicAdd(pVI + m*3 + 2, wv * sh.w);
    }
    #pragma unroll
    for (int m = 0; m < 16; ++m) atomicAdd(pSJ + m, wgt[32+m] * sh.x);
    #pragma unroll
    for (int m = 0; m < 16; ++m) {
        const float wv = wgt[48+m];
        atomicAdd(pVJ + m*3 + 0, wv * sh.y);
        atomicAdd(pVJ + m*3 + 1, wv * sh.z);
        atomicAdd(pVJ + m*3 + 2, wv * sh.w);
    }
}

// ---------------------------------------------------------------------------
// Stage B: 64 edges/block, 512 threads = 8 waves.
//   waves 0..3: o_s outputs m0=w*12 .. +11   (ss K=1024 + vv K=512)
//   waves 4..7: o_v outputs o0=(w-4)*4 .. +3 (sv + vs), 3 comps each
// ---------------------------------------------------------------------------
extern "C" __global__ void __launch_bounds__(512, 4)
k_contract(const float* __restrict__ edge_fea,
           const int* __restrict__ idx_i,
           const int* __restrict__ idx_j,
           const float* __restrict__ nsI, const float* __restrict__ nsJ,
           const float* __restrict__ nvI, const float* __restrict__ nvJ,
           const float* __restrict__ w_ss, const float* __restrict__ w_vv,
           const float* __restrict__ w_sv, const float* __restrict__ w_vs,
           float* __restrict__ out)
{
    __shared__ float lds[13312];            // 53.25 KB -> 3 blocks/CU by LDS
    float* sS1 = lds;                       // [32][64]
    float* sS2 = lds + 2048;                // [32][64]
    float* sV1 = lds + 4096;                // [96][64]  (c*32+i)
    float* sV2 = lds + 10240;               // [48][64]  (c*16+j)
    float* sOs = lds + 4096;                // alias over sV1 rows 0..47
    float* sOv = lds + 7168;                // alias over sV1 rows 48..95

    const int tid = threadIdx.x;
    const int e0 = blockIdx.x * 64;
    const int lane = tid & 63;

    // ---- gather S2 / V2 from edge_fea ----
    for (int t = tid; t < 64*20; t += 512) {
        const int e = t & 63, q = t >> 6;
        const float4 v = *reinterpret_cast<const float4*>(
            edge_fea + (size_t)(e0 + e) * 80 + q * 4);
        const float vv[4] = {v.x, v.y, v.z, v.w};
        #pragma unroll
        for (int u = 0; u < 4; ++u) {
            const int f = q*4 + u;
            if (f < 32) {
                sS2[f*64 + e] = vv[u];
            } else {
                const int r = f - 32;           // r = j*3 + c
                sV2[((r % 3)*16 + (r / 3))*64 + e] = vv[u];
            }
        }
    }
    // ---- gather S1 ----
    for (int t = tid; t < 64*32; t += 512) {
        const int e = t & 63, i = t >> 6;
        float v;
        if (i < 16) v = nsI[idx_i[e0+e]*16 + i];
        else        v = nsJ[idx_j[e0+e]*16 + (i - 16)];
        sS1[i*64 + e] = v;
    }
    // ---- gather V1 ----
    for (int t = tid; t < 64*96; t += 512) {
        const int e = t & 63, r = t >> 6;   // r = i*3+c
        const int i = r / 3, c = r % 3;
        float v;
        if (i < 16) v = nvI[(idx_i[e0+e]*16 + i)*3 + c];
        else        v = nvJ[(idx_j[e0+e]*16 + (i - 16))*3 + c];
        sV1[(c*32 + i)*64 + e] = v;
    }
    __syncthreads();

    const int w = __builtin_amdgcn_readfirstlane(tid >> 6);
    const float INV2 = 0.70710678118654752f;
    const float RS512 = 22.627416997969522f;     // sqrt(512)
    const int m0 = (w < 4) ? (w * 12) : 0;
    const int o0 = (w >= 4) ? ((w - 4) * 4) : 0;

    float acc[12];
    #pragma unroll
    for (int m = 0; m < 12; ++m) acc[m] = 0.0f;

    if (w < 4) {
        // ---------------- o_s: ss (K=1024) + vv (K=512) ----------------
        const float aSS = INV2 / 32.0f;
        const float aVV = INV2 * 0.57735026918962576f / RS512;
        const float* wssb = w_ss + (size_t)m0 * 1024;
        for (int i = 0; i < 32; ++i) {
            const float s1 = aSS * sS1[i*64 + lane];
            #pragma unroll 1
            for (int j = 0; j < 32; j += 4) {
                const float x0 = s1 * sS2[(j+0)*64 + lane];
                const float x1 = s1 * sS2[(j+1)*64 + lane];
                const float x2 = s1 * sS2[(j+2)*64 + lane];
                const float x3 = s1 * sS2[(j+3)*64 + lane];
                #pragma unroll
                for (int m = 0; m < 12; ++m) {
                    const float* wp = wssb + m*1024 + i*32 + j;
                    acc[m] = fmaf(x0, wp[0], acc[m]);
                    acc[m] = fmaf(x1, wp[1], acc[m]);
                    acc[m] = fmaf(x2, wp[2], acc[m]);
                    acc[m] = fmaf(x3, wp[3], acc[m]);
                }
            }
        }
        const float* wvvb = w_vv + (size_t)m0 * 512;
        for (int i = 0; i < 32; ++i) {
            const float v1c0 = aVV * sV1[(0*32 + i)*64 + lane];
            const float v1c1 = aVV * sV1[(1*32 + i)*64 + lane];
            const float v1c2 = aVV * sV1[(2*32 + i)*64 + lane];
            #pragma unroll 1
            for (int j = 0; j < 16; j += 4) {
                float x[4];
                #pragma unroll
                for (int u = 0; u < 4; ++u) {
                    x[u] = v1c0 * sV2[(0*16 + j + u)*64 + lane]
                         + v1c1 * sV2[(1*16 + j + u)*64 + lane]
                         + v1c2 * sV2[(2*16 + j + u)*64 + lane];
                }
                #pragma unroll
                for (int m = 0; m < 12; ++m) {
                    const float* wp = wvvb + m*512 + i*16 + j;
                    acc[m] = fmaf(x[0], wp[0], acc[m]);
                    acc[m] = fmaf(x[1], wp[1], acc[m]);
                    acc[m] = fmaf(x[2], wp[2], acc[m]);
                    acc[m] = fmaf(x[3], wp[3], acc[m]);
                }
            }
        }
    } else {
        // ---------------- o_v: sv (K=512/c) + vs (K=1024/c) ----------------
        const float aSV = INV2 / RS512;
        const float aVS = INV2 / 32.0f;
        const float* wsvb = w_sv + (size_t)o0 * 512;
        for (int i = 0; i < 32; ++i) {
            const float s1 = aSV * sS1[i*64 + lane];
            #pragma unroll 1
            for (int j = 0; j < 16; j += 4) {
                float x[4][3];
                #pragma unroll
                for (int u = 0; u < 4; ++u) {
                    x[u][0] = s1 * sV2[(0*16 + j + u)*64 + lane];
                    x[u][1] = s1 * sV2[(1*16 + j + u)*64 + lane];
                    x[u][2] = s1 * sV2[(2*16 + j + u)*64 + lane];
                }
                #pragma unroll
                for (int m = 0; m < 4; ++m) {
                    const float* wp = wsvb + m*512 + i*16 + j;
                    #pragma unroll
                    for (int u = 0; u < 4; ++u) {
                        const float wq = wp[u];
                        acc[m*3+0] = fmaf(x[u][0], wq, acc[m*3+0]);
                        acc[m*3+1] = fmaf(x[u][1], wq, acc[m*3+1]);
                        acc[m*3+2] = fmaf(x[u][2], wq, acc[m*3+2]);
                    }
                }
            }
        }
        const float* wvsb = w_vs + (size_t)o0 * 1024;
        for (int i = 0; i < 32; ++i) {
            const float v1c0 = sV1[(0*32 + i)*64 + lane];
            const float v1c1 = sV1[(1*32 + i)*64 + lane];
            const float v1c2 = sV1[(2*32 + i)*64 + lane];
            #pragma unroll 1
            for (int j = 0; j < 32; j += 4) {
                float x[4][3];
                #pragma unroll
                for (int u = 0; u < 4; ++u) {
                    const float s2 = aVS * sS2[(j + u)*64 + lane];
                    x[u][0] = v1c0 * s2;
                    x[u][1] = v1c1 * s2;
                    x[u][2] = v1c2 * s2;
                }
                #pragma unroll
                for (int m = 0; m < 4; ++m) {
                    const float* wp = wvsb + m*1024 + i*32 + j;
                    #pragma unroll
                    for (int u = 0; u < 4; ++u) {
                        const float wq = wp[u];
                        acc[m*3+0] = fmaf(x[u][0], wq, acc[m*3+0]);
                        acc[m*3+1] = fmaf(x[u][1], wq, acc[m*3+1]);
                        acc[m*3+2] = fmaf(x[u][2], wq, acc[m*3+2]);
                    }
                }
            }
        }
    }

    __syncthreads();   // done reading sV1/sV2 before alias-write

    if (w < 4) {
        #pragma unroll
        for (int m = 0; m < 12; ++m) sOs[(m0 + m)*64 + lane] = acc[m];
    } else {
        #pragma unroll
        for (int m = 0; m < 4; ++m) {
            #pragma unroll
            for (int c = 0; c < 3; ++c)
                sOv[((o0 + m)*3 + c)*64 + lane] = acc[m*3 + c];
        }
    }
    __syncthreads();

    // ---- epilogue: silu(o_s[:32]), o_v * sigmoid(o_s[32:48]) ----
    for (int t = tid; t < 64*80; t += 512) {
        const int e = t & 63, f = t >> 6;
        float r;
        if (f < 32) {
            const float x = sOs[f*64 + e];
            r = x * fsigmoid(x);
        } else {
            const int rr = f - 32;              // rr = o*3 + c
            const int o = rr / 3;
            r = sOv[rr*64 + e] * fsigmoid(sOs[(32 + o)*64 + e]);
        }
        out[(size_t)(e0 + e)*80 + f] = r;
    }
}

extern "C" void kernel_launch(void* const* d_in, const int* in_sizes, int n_in,
                              void* d_out, int out_size, void* d_ws, size_t ws_size,
                              hipStream_t stream)
{
    const float* edge_sh  = (const float*)d_in[0];
    const float* edge_fea = (const float*)d_in[1];
    const int*   eidx     = (const int*)d_in[2];
    // d_in[3] = batch_edge (unused)
    const float* w1 = (const float*)d_in[4];
    const float* b1 = (const float*)d_in[5];
    const float* w2 = (const float*)d_in[6];
    const float* b2 = (const float*)d_in[7];
    const float* w3 = (const float*)d_in[8];
    const float* b3 = (const float*)d_in[9];
    const float* w_ss = (const float*)d_in[10];
    const float* w_vv = (const float*)d_in[11];
    const float* w_sv = (const float*)d_in[12];
    const float* w_vs = (const float*)d_in[13];
    float* out = (float*)d_out;

    float* ws  = (float*)d_ws;
    float* nsI = ws;                 // [10000][16]
    float* nsJ = ws + 160000;        // [10000][16]
    float* nvI = ws + 320000;        // [10000][16][3]
    float* nvJ = ws + 800000;        // [10000][16][3]

    // fast-path extra workspace
    float* wgtbuf = ws + 1280000;                // [160000][64]
    float* shbuf  = ws + 11520000;               // [160000][4]
    int*   counts  = (int*)(ws + 12160000);      // [10000]
    int*   offsets = counts + NNODES;            // [10001]
    int*   cursor  = offsets + NNODES + 1;       // [10000]
    const size_t need = (size_t)(12160000 + 3*NNODES + 1) * 4;

    if (ws_size >= need) {
        hipMemsetAsync(counts, 0, NNODES * sizeof(int), stream);
        k_hist<<<625, 256, 0, stream>>>(eidx, counts);
        k_scan<<<1, 256, 0, stream>>>(counts, offsets, cursor);
        k_mlp_store<<<625, 256, 0, stream>>>(edge_sh, edge_fea, eidx,
                                             w1, b1, w2, b2, w3, b3,
                                             cursor, wgtbuf, shbuf);
        k_reduce<<<NNODES/2, 256, 0, stream>>>(offsets, wgtbuf, shbuf,
                                               nsI, nsJ, nvI, nvJ);
    } else {
        hipMemsetAsync(d_ws, 0, 1280000 * sizeof(float), stream);
        k_mlp_scatter<<<625, 256, 0, stream>>>(edge_sh, edge_fea, eidx,
                                               w1, b1, w2, b2, w3, b3,
                                               nsI, nsJ, nvI, nvJ);
    }

    k_contract<<<2500, 512, 0, stream>>>(edge_fea, eidx, eidx + EDGES,
                                         nsI, nsJ, nvI, nvJ,
                                         w_ss, w_vv, w_sv, w_vs, out);
}

// Round 4
// 696.459 us; speedup vs baseline: 3.1908x; 1.8222x over previous
//
#include <hip/hip_runtime.h>
#include <hip/hip_bf16.h>

#define EDGES 160000
#define NNODES 10000

typedef __attribute__((ext_vector_type(8))) short short8;
typedef __attribute__((ext_vector_type(4))) float f32x4;

__device__ __forceinline__ float fsigmoid(float x) {
    return 1.0f / (1.0f + __expf(-x));
}

union F8 { uint32_t u[4]; short8 s8; };

// packed bf16 pair: low16 = bf16(e0), high16 = bf16(e1), RNE
__device__ __forceinline__ uint32_t pk2(float e0, float e1) {
    uint32_t r;
    asm("v_cvt_pk_bf16_f32 %0, %1, %2" : "=v"(r) : "v"(e0), "v"(e1));
    return r;
}

// Dekker-style split of 8 fp32 into bf16 hi + bf16 lo fragments
__device__ __forceinline__ void split8(const float* x, F8& ah, F8& al) {
    #pragma unroll
    for (int r = 0; r < 4; ++r) {
        const float x0 = x[2*r], x1 = x[2*r+1];
        const uint32_t h = pk2(x0, x1);
        ah.u[r] = h;
        const float f0 = __uint_as_float(h << 16);
        const float f1 = __uint_as_float(h & 0xffff0000u);
        al.u[r] = pk2(x0 - f0, x1 - f1);
    }
}

__device__ __forceinline__ f32x4 mm(const F8& a, const F8& b, f32x4 c) {
    return __builtin_amdgcn_mfma_f32_16x16x32_bf16(a.s8, b.s8, c, 0, 0, 0);
}

__device__ __forceinline__ void ld_b(const uint4* p, int idx, F8& d) {
    const uint4 v = p[idx];
    d.u[0] = v.x; d.u[1] = v.y; d.u[2] = v.z; d.u[3] = v.w;
}

// ---------------------------------------------------------------------------
// MLP evaluation: edge e -> wgt[64]
// ---------------------------------------------------------------------------
__device__ __forceinline__ void mlp_eval(int e,
              const float* __restrict__ edge_fea,
              const float* __restrict__ w1, const float* __restrict__ b1,
              const float* __restrict__ w2, const float* __restrict__ b2,
              const float* __restrict__ w3, const float* __restrict__ b3,
              float* wgt)
{
    float s[32];
    const float4* f4 = reinterpret_cast<const float4*>(edge_fea + (size_t)e * 80);
    #pragma unroll
    for (int q = 0; q < 8; ++q) {
        float4 v = f4[q];
        s[4*q+0] = v.x; s[4*q+1] = v.y; s[4*q+2] = v.z; s[4*q+3] = v.w;
    }
    float h[64];
    #pragma unroll
    for (int k = 0; k < 64; ++k) h[k] = b1[k];
    #pragma unroll
    for (int i = 0; i < 32; ++i) {
        const float si = s[i];
        #pragma unroll
        for (int k = 0; k < 64; ++k) h[k] = fmaf(si, w1[i*64+k], h[k]);
    }
    #pragma unroll
    for (int k = 0; k < 64; ++k) h[k] = h[k] * fsigmoid(h[k]);
    float h2[64];
    #pragma unroll
    for (int k = 0; k < 64; ++k) h2[k] = b2[k];
    #pragma unroll
    for (int i = 0; i < 64; ++i) {
        const float si = h[i];
        #pragma unroll
        for (int k = 0; k < 64; ++k) h2[k] = fmaf(si, w2[i*64+k], h2[k]);
    }
    #pragma unroll
    for (int k = 0; k < 64; ++k) h2[k] = h2[k] * fsigmoid(h2[k]);
    #pragma unroll
    for (int k = 0; k < 64; ++k) wgt[k] = b3[k];
    #pragma unroll
    for (int i = 0; i < 64; ++i) {
        const float si = h2[i];
        #pragma unroll
        for (int k = 0; k < 64; ++k) wgt[k] = fmaf(si, w3[i*64+k], wgt[k]);
    }
}

// ---------------------------------------------------------------------------
// Stage A: CSR build + MLP->slot store + gather reduce (proven in round 2)
// ---------------------------------------------------------------------------
extern "C" __global__ void __launch_bounds__(256)
k_hist(const int* __restrict__ idx_i, int* __restrict__ counts)
{
    const int e = blockIdx.x * 256 + threadIdx.x;
    if (e < EDGES) atomicAdd(&counts[idx_i[e]], 1);
}

extern "C" __global__ void __launch_bounds__(256)
k_scan(const int* __restrict__ counts, int* __restrict__ offsets,
       int* __restrict__ cursor)
{
    __shared__ int sc[2][256];
    const int t = threadIdx.x;
    const int base = t * 40;
    int loc[40];
    int s = 0;
    #pragma unroll
    for (int k = 0; k < 40; ++k) {
        const int idx = base + k;
        const int c = (idx < NNODES) ? counts[idx] : 0;
        loc[k] = c; s += c;
    }
    sc[0][t] = s;
    __syncthreads();
    int src = 0;
    for (int off = 1; off < 256; off <<= 1) {
        int v = sc[src][t];
        if (t >= off) v += sc[src][t - off];
        sc[src ^ 1][t] = v;
        __syncthreads();
        src ^= 1;
    }
    int run = sc[src][t] - s;          // exclusive prefix
    #pragma unroll
    for (int k = 0; k < 40; ++k) {
        const int idx = base + k;
        if (idx < NNODES) {
            offsets[idx] = run;
            cursor[idx]  = run;
            run += loc[k];
        }
    }
    if (t == 255) offsets[NNODES] = EDGES;
}

extern "C" __global__ void __launch_bounds__(256)
k_mlp_store(const float* __restrict__ edge_sh,
            const float* __restrict__ edge_fea,
            const int* __restrict__ idx_i,
            const float* __restrict__ w1, const float* __restrict__ b1,
            const float* __restrict__ w2, const float* __restrict__ b2,
            const float* __restrict__ w3, const float* __restrict__ b3,
            int* __restrict__ cursor,
            float* __restrict__ wgtbuf, float* __restrict__ shbuf)
{
    const int e = blockIdx.x * 256 + threadIdx.x;
    float wgt[64];
    mlp_eval(e, edge_fea, w1, b1, w2, b2, w3, b3, wgt);

    const int ni = idx_i[e];
    const int slot = atomicAdd(&cursor[ni], 1);
    float4* wp = reinterpret_cast<float4*>(wgtbuf + (size_t)slot * 64);
    #pragma unroll
    for (int q = 0; q < 16; ++q)
        wp[q] = make_float4(wgt[4*q], wgt[4*q+1], wgt[4*q+2], wgt[4*q+3]);
    *reinterpret_cast<float4*>(shbuf + (size_t)slot * 4) =
        *reinterpret_cast<const float4*>(edge_sh + (size_t)e * 4);
}

extern "C" __global__ void __launch_bounds__(256)
k_reduce(const int* __restrict__ offsets,
         const float* __restrict__ wgtbuf, const float* __restrict__ shbuf,
         float* __restrict__ nsI, float* __restrict__ nsJ,
         float* __restrict__ nvI, float* __restrict__ nvJ)
{
    const int tid = threadIdx.x;
    const int n = blockIdx.x * 2 + (tid >> 7);
    const int o = tid & 127;

    int widx, shc;
    float* dst;
    if (o < 16)      { widx = o;            shc = 0;     dst = &nsI[n*16 + o]; }
    else if (o < 64) { const int r = o - 16; const int m = r / 3, c = r - 3*m;
                       widx = 16 + m;       shc = 1 + c; dst = &nvI[(n*16 + m)*3 + c]; }
    else if (o < 80) { const int r = o - 64;
                       widx = 32 + r;       shc = 0;     dst = &nsJ[n*16 + r]; }
    else             { const int r = o - 80; const int m = r / 3, c = r - 3*m;
                       widx = 48 + m;       shc = 1 + c; dst = &nvJ[(n*16 + m)*3 + c]; }

    const int s0 = offsets[n], s1 = offsets[n + 1];
    float acc = 0.0f;
    for (int s = s0; s < s1; ++s)
        acc = fmaf(wgtbuf[(size_t)s*64 + widx], shbuf[(size_t)s*4 + shc], acc);
    *dst = acc;
}

// ---------------------------------------------------------------------------
// k_pack: weights -> MFMA B-fragment layout, bf16 hi/lo split, scales folded.
// Fragment index: segbase + ((kc*tiles + tile)*2 + h)*64 + lane  (uint4 each)
//   lane l: o = tile*16 + (l&15), k = kc*32 + (l>>4)*8 + [0..8)
//   uint4 word r = pk(bf16(k=2r), bf16(k=2r+1))
// segs: ss[K=1024,t=3]@0  vv[512,3]@12288  sv[512,1]@18432  vs[1024,1]@20480
// ---------------------------------------------------------------------------
extern "C" __global__ void __launch_bounds__(256)
k_pack(const float* __restrict__ w_ss, const float* __restrict__ w_vv,
       const float* __restrict__ w_sv, const float* __restrict__ w_vs,
       uint4* __restrict__ pk)
{
    const int t = blockIdx.x * 256 + threadIdx.x;     // [0, 24576)
    const float INV2  = 0.70710678118654752f;
    const float RS512 = 22.627416997969522f;
    const float C3    = 0.57735026918962576f;

    const float* W; int K; float scale; int local; int tiles;
    if (t < 12288)      { W = w_ss; K = 1024; scale = INV2/32.0f;     local = t;         tiles = 3; }
    else if (t < 18432) { W = w_vv; K = 512;  scale = INV2*C3/RS512;  local = t - 12288; tiles = 3; }
    else if (t < 20480) { W = w_sv; K = 512;  scale = INV2/RS512;     local = t - 18432; tiles = 1; }
    else                { W = w_vs; K = 1024; scale = INV2/32.0f;     local = t - 20480; tiles = 1; }

    const int l    = local & 63;
    const int h    = (local >> 6) & 1;
    const int rest = local >> 7;               // kc*tiles + tile
    const int tile = rest % tiles;
    const int kc   = rest / tiles;
    const int o    = tile*16 + (l & 15);
    const int kb   = kc*32 + (l >> 4)*8;

    const float4* src = reinterpret_cast<const float4*>(W + (size_t)o * K + kb);
    const float4 a = src[0], b = src[1];
    const float v[8] = {a.x, a.y, a.z, a.w, b.x, b.y, b.z, b.w};

    uint32_t out[4];
    #pragma unroll
    for (int r = 0; r < 4; ++r) {
        const float x0 = v[2*r] * scale, x1 = v[2*r+1] * scale;
        const uint32_t hi = pk2(x0, x1);
        if (h == 0) out[r] = hi;
        else {
            const float f0 = __uint_as_float(hi << 16);
            const float f1 = __uint_as_float(hi & 0xffff0000u);
            out[r] = pk2(x0 - f0, x1 - f1);
        }
    }
    pk[t] = make_uint4(out[0], out[1], out[2], out[3]);
}

// ---------------------------------------------------------------------------
// Stage B: MFMA contraction. 64 edges/block, 8 waves.
//   waves 0..3 (edge-quarter q): o_s — G1 (S1 x S2, K=1024) + G2 (sum_c V1c x V2c,
//     K=512), 3 N-tiles of 16 outputs, acc[3] f32x4.
//   waves 4..7 (edge-quarter q): o_v — G3 (S1 x V2c, K=512) + G4 (V1c x S2,
//     K=1024), 1 N-tile, 3 components c, acc[3] f32x4. B shared across c.
// A split into bf16 hi/lo, W pre-split -> 3 MFMA per (chunk, tile): hh, lh, hl.
// ---------------------------------------------------------------------------
extern "C" __global__ void __launch_bounds__(512)
k_contract(const float* __restrict__ edge_fea,
           const int* __restrict__ idx_i, const int* __restrict__ idx_j,
           const float* __restrict__ nsI, const float* __restrict__ nsJ,
           const float* __restrict__ nvI, const float* __restrict__ nvJ,
           const uint4* __restrict__ pk,
           float* __restrict__ out)
{
    __shared__ float lds[13568];              // 54272 B -> 3 blocks/CU by LDS
    float* sS1T = lds;                        // [32][64]
    float* sS2  = lds + 2048;                 // [64][33] (+1 pad)
    float* sV1T = lds + 4160;                 // [3][32][64]
    float* sV2  = lds + 10304;                // [3][64][17] (+1 pad)
    float* sOs  = lds;                        // [48][65] reuse (epilogue)
    float* sOv  = lds + 4160;                 // [48][65] reuse (epilogue)

    const int tid = threadIdx.x;
    const int e0  = blockIdx.x * 64;

    // ---- gather S2 / V2 from edge_fea ----
    for (int t = tid; t < 64*20; t += 512) {
        const int ge = t & 63, qd = t >> 6;
        const float4 v = *reinterpret_cast<const float4*>(
            edge_fea + (size_t)(e0 + ge) * 80 + qd * 4);
        const float vv4[4] = {v.x, v.y, v.z, v.w};
        #pragma unroll
        for (int u = 0; u < 4; ++u) {
            const int f = qd*4 + u;
            if (f < 32) sS2[ge*33 + f] = vv4[u];
            else {
                const int r = f - 32;               // r = j*3 + c
                sV2[(r % 3)*1088 + ge*17 + r/3] = vv4[u];
            }
        }
    }
    // ---- gather S1 (transposed) ----
    for (int t = tid; t < 2048; t += 512) {
        const int ge = t & 63, i = t >> 6;
        const float v = (i < 16) ? nsI[idx_i[e0+ge]*16 + i]
                                 : nsJ[idx_j[e0+ge]*16 + (i - 16)];
        sS1T[i*64 + ge] = v;
    }
    // ---- gather V1 (transposed) ----
    for (int t = tid; t < 6144; t += 512) {
        const int ge = t & 63, r = t >> 6;    // r = i*3 + c
        const int i = r / 3, c = r % 3;
        const float v = (i < 16) ? nvI[(idx_i[e0+ge]*16 + i)*3 + c]
                                 : nvJ[(idx_j[e0+ge]*16 + (i - 16))*3 + c];
        sV1T[c*2048 + i*64 + ge] = v;
    }
    __syncthreads();

    const int w  = tid >> 6;                  // wave 0..7
    const int l  = tid & 63;
    const int q  = w & 3;                     // edge quarter
    const int e  = q*16 + (l & 15);           // this lane's A-row edge
    const int ks = l >> 4;                    // k-slice 0..3

    const uint4* Bss = pk;
    const uint4* Bvv = pk + 12288;
    const uint4* Bsv = pk + 18432;
    const uint4* Bvs = pk + 20480;

    // register slices (fixed per lane)
    float s2r[8];
    #pragma unroll
    for (int u = 0; u < 8; ++u) s2r[u] = sS2[e*33 + ks*8 + u];
    float v2r[3][8];
    #pragma unroll
    for (int c = 0; c < 3; ++c)
        #pragma unroll
        for (int u = 0; u < 8; ++u)
            v2r[c][u] = sV2[c*1088 + e*17 + (ks & 1)*8 + u];

    f32x4 acc[3] = {{0,0,0,0},{0,0,0,0},{0,0,0,0}};

    if (w < 4) {
        // ---------------- o_s ----------------
        // G1: A[k=i*32+j] = S1[i] * S2[j]
        for (int i = 0; i < 32; ++i) {
            const float s1 = sS1T[i*64 + e];
            float x[8];
            #pragma unroll
            for (int u = 0; u < 8; ++u) x[u] = s1 * s2r[u];
            F8 ah, al; split8(x, ah, al);
            #pragma unroll
            for (int t = 0; t < 3; ++t) {
                F8 bh, bl;
                ld_b(Bss, ((i*3 + t)*2 + 0)*64 + l, bh);
                ld_b(Bss, ((i*3 + t)*2 + 1)*64 + l, bl);
                acc[t] = mm(ah, bh, acc[t]);
                acc[t] = mm(al, bh, acc[t]);
                acc[t] = mm(ah, bl, acc[t]);
            }
        }
        // G2: A[k=i*16+j] = sum_c V1c[i] * V2c[j]
        for (int n = 0; n < 16; ++n) {
            const int i = 2*n + (ks >> 1);
            const float a0 = sV1T[0*2048 + i*64 + e];
            const float a1 = sV1T[1*2048 + i*64 + e];
            const float a2 = sV1T[2*2048 + i*64 + e];
            float x[8];
            #pragma unroll
            for (int u = 0; u < 8; ++u)
                x[u] = fmaf(a2, v2r[2][u], fmaf(a1, v2r[1][u], a0 * v2r[0][u]));
            F8 ah, al; split8(x, ah, al);
            #pragma unroll
            for (int t = 0; t < 3; ++t) {
                F8 bh, bl;
                ld_b(Bvv, ((n*3 + t)*2 + 0)*64 + l, bh);
                ld_b(Bvv, ((n*3 + t)*2 + 1)*64 + l, bl);
                acc[t] = mm(ah, bh, acc[t]);
                acc[t] = mm(al, bh, acc[t]);
                acc[t] = mm(ah, bl, acc[t]);
            }
        }
    } else {
        // ---------------- o_v ----------------
        // G3: A_c[k=i*16+j] = S1[i] * V2c[j]
        for (int n = 0; n < 16; ++n) {
            const int i = 2*n + (ks >> 1);
            const float s1 = sS1T[i*64 + e];
            F8 bh, bl;
            ld_b(Bsv, (n*2 + 0)*64 + l, bh);
            ld_b(Bsv, (n*2 + 1)*64 + l, bl);
            #pragma unroll
            for (int c = 0; c < 3; ++c) {
                float x[8];
                #pragma unroll
                for (int u = 0; u < 8; ++u) x[u] = s1 * v2r[c][u];
                F8 ah, al; split8(x, ah, al);
                acc[c] = mm(ah, bh, acc[c]);
                acc[c] = mm(al, bh, acc[c]);
                acc[c] = mm(ah, bl, acc[c]);
            }
        }
        // G4: A_c[k=i*32+j] = V1c[i] * S2[j]
        for (int i = 0; i < 32; ++i) {
            F8 bh, bl;
            ld_b(Bvs, (i*2 + 0)*64 + l, bh);
            ld_b(Bvs, (i*2 + 1)*64 + l, bl);
            #pragma unroll
            for (int c = 0; c < 3; ++c) {
                const float v1 = sV1T[c*2048 + i*64 + e];
                float x[8];
                #pragma unroll
                for (int u = 0; u < 8; ++u) x[u] = v1 * s2r[u];
                F8 ah, al; split8(x, ah, al);
                acc[c] = mm(ah, bh, acc[c]);
                acc[c] = mm(al, bh, acc[c]);
                acc[c] = mm(ah, bl, acc[c]);
            }
        }
    }

    __syncthreads();   // all waves done reading LDS sources

    // D layout: col = output = l&15, rows = edges q*16 + ks*4 + r
    if (w < 4) {
        #pragma unroll
        for (int t = 0; t < 3; ++t)
            #pragma unroll
            for (int r = 0; r < 4; ++r)
                sOs[(t*16 + (l & 15))*65 + q*16 + ks*4 + r] = acc[t][r];
    } else {
        #pragma unroll
        for (int c = 0; c < 3; ++c)
            #pragma unroll
            for (int r = 0; r < 4; ++r)
                sOv[((l & 15)*3 + c)*65 + q*16 + ks*4 + r] = acc[c][r];
    }
    __syncthreads();

    // ---- epilogue: silu(o_s[:32]), o_v * sigmoid(o_s[32:48]) — coalesced ----
    for (int t = tid; t < 64*80; t += 512) {
        const int ge = t / 80, f = t % 80;
        float r;
        if (f < 32) {
            const float xv = sOs[f*65 + ge];
            r = xv * fsigmoid(xv);
        } else {
            const int rr = f - 32;                 // rr = o*3 + c
            const int o  = rr / 3;
            r = sOv[rr*65 + ge] * fsigmoid(sOs[(32 + o)*65 + ge]);
        }
        out[(size_t)(e0 + ge)*80 + f] = r;
    }
}

extern "C" void kernel_launch(void* const* d_in, const int* in_sizes, int n_in,
                              void* d_out, int out_size, void* d_ws, size_t ws_size,
                              hipStream_t stream)
{
    const float* edge_sh  = (const float*)d_in[0];
    const float* edge_fea = (const float*)d_in[1];
    const int*   eidx     = (const int*)d_in[2];
    // d_in[3] = batch_edge (unused)
    const float* w1 = (const float*)d_in[4];
    const float* b1 = (const float*)d_in[5];
    const float* w2 = (const float*)d_in[6];
    const float* b2 = (const float*)d_in[7];
    const float* w3 = (const float*)d_in[8];
    const float* b3 = (const float*)d_in[9];
    const float* w_ss = (const float*)d_in[10];
    const float* w_vv = (const float*)d_in[11];
    const float* w_sv = (const float*)d_in[12];
    const float* w_vs = (const float*)d_in[13];
    float* out = (float*)d_out;

    float* ws  = (float*)d_ws;
    float* nsI = ws;                             // [10000][16]
    float* nsJ = ws + 160000;                    // [10000][16]
    float* nvI = ws + 320000;                    // [10000][16][3]
    float* nvJ = ws + 800000;                    // [10000][16][3]
    float* wgtbuf = ws + 1280000;                // [160000][64]
    float* shbuf  = ws + 11520000;               // [160000][4]
    int*   counts  = (int*)(ws + 12160000);      // [10000]
    int*   offsets = counts + NNODES;            // [10001]
    int*   cursor  = offsets + NNODES + 1;       // [10000]
    // packed B-fragments reuse the wgtbuf region (dead after k_reduce);
    // 24576 uint4 = 384 KB, offset 5,120,000 B is 16B-aligned.
    uint4* pkbuf = (uint4*)wgtbuf;

    hipMemsetAsync(counts, 0, NNODES * sizeof(int), stream);
    k_hist<<<625, 256, 0, stream>>>(eidx, counts);
    k_scan<<<1, 256, 0, stream>>>(counts, offsets, cursor);
    k_mlp_store<<<625, 256, 0, stream>>>(edge_sh, edge_fea, eidx,
                                         w1, b1, w2, b2, w3, b3,
                                         cursor, wgtbuf, shbuf);
    k_reduce<<<NNODES/2, 256, 0, stream>>>(offsets, wgtbuf, shbuf,
                                           nsI, nsJ, nvI, nvJ);
    k_pack<<<96, 256, 0, stream>>>(w_ss, w_vv, w_sv, w_vs, pkbuf);
    k_contract<<<2500, 512, 0, stream>>>(edge_fea, eidx, eidx + EDGES,
                                         nsI, nsJ, nvI, nvJ, pkbuf, out);
}